// Round 11
// baseline (48.363 us; speedup 1.0000x reference)
//
#include <hip/hip_runtime.h>

// Problem constants
#define NSTEPS 255
#define NTRAJ  16384
#define NGRP   32           // output groups = blocks; 512 trajectories each

#define GAMMA_F 0.36f
#define OMEGA_F 5.0265f
#define DT_F    0.00390625f          // 2^-8
#define CW      0.0375f              // sqrt(GAMMA)*sqrt(DT) = 0.6/16 (exact)
#define GD      (GAMMA_F * DT_F)
#define OD      (OMEGA_F * DT_F)

// LDS history window: [slot 0..31][traj 0..511] fp16x4 {x,y,z,pad}.
// Slot pitch 4096 B. Writes: 512 lanes consecutive 8B (2-way = free).
// Tail reads: lane l reads j = l + 64m, consecutive 8B per wave (free).
#define HSLOT  4096
#define HBYTES (32 * HSLOT)   // 131072 B

typedef __fp16 half2v __attribute__((ext_vector_type(2)));
typedef float  f32x2  __attribute__((ext_vector_type(2)));

__device__ __forceinline__ unsigned pk2(float a, float b) {
  half2v h = __builtin_amdgcn_cvt_pkrtz(a, b);
  return __builtin_bit_cast(unsigned, h);
}

// ---- DPP wave64 sum (R1-validated): result lands in lane 63 ----
template<int CTRL, int RM>
__device__ __forceinline__ float dpp_add(float v) {
  int sh = __builtin_amdgcn_update_dpp(0, __float_as_int(v), CTRL, RM, 0xf, true);
  return v + __int_as_float(sh);
}

__device__ __forceinline__ float wave_sum64(float v) {
  v = dpp_add<0x111, 0xf>(v);  // row_shr:1
  v = dpp_add<0x112, 0xf>(v);  // row_shr:2
  v = dpp_add<0x114, 0xf>(v);  // row_shr:4
  v = dpp_add<0x118, 0xf>(v);  // row_shr:8
  v = dpp_add<0x142, 0xa>(v);  // row_bcast:15
  v = dpp_add<0x143, 0xc>(v);  // row_bcast:31 -> lane63 = total
  return v;
}

// One Euler-Maruyama step (bit-identical to R4/R7/R9 validated math).
// Writes fp16x4 state for local slot ii_ to hist.
#define STEP2(wx_, wy_, ii_) {                                                  \
  const float w0  = (wx_) * CW;                                                 \
  const float cy  = (wy_) * CW;                                                 \
  const f32x2 sw  = __builtin_shufflevector(v, v, 1, 0);   /* (y,x) */          \
  f32x2 t = __builtin_elementwise_fma(epack, sw, v);                            \
  t = __builtin_elementwise_fma(mGD2, v, t);                                    \
  const f32x2 w0s = {w0, w0};                                                   \
  t = __builtin_elementwise_fma(-(v * z), w0s, t);                              \
  const f32x2 cys = {-cy, cy};                                                  \
  t = __builtin_elementwise_fma(sw, cys, t);                                    \
  t[1] = __builtin_fmaf(-OD, z, t[1]);                                          \
  const float a_ = __builtin_fmaf(OD, v[1], z);                                 \
  const float r_ = __builtin_fmaf(-(z * z), w0, w0);                            \
  v = t; z = a_ + r_;                                                           \
  *(uint2*)(hb + (ii_) * HSLOT) = make_uint2(pk2(v[0], v[1]), pk2(z, 0.0f));    \
}

// Load CNT w-entries of window WI into reg buffer (thread's own row; 8-aligned)
#define LOADW(BUF, WI, CNT) {                                                   \
  _Pragma("unroll")                                                             \
  for (int i_ = 0; i_ < (CNT); ++i_) BUF[i_] = wrow[(WI) * 32 + i_];            \
}

// Run CNT steps from reg buffer (CNT compile-time: 32 or 31)
#define PROCW(BUF, CNT) {                                                       \
  _Pragma("unroll")                                                             \
  for (int i_ = 0; i_ < (CNT); ++i_) STEP2((BUF)[i_].x, (BUF)[i_].y, i_)        \
}

// Window tail: wave wid reduces slots wid+8k (k=0..3) over 512 trajectories;
// lane 63 writes the 6 probabilities for t = w*32 + slot + 1.
#define TAILW(w_) {                                                             \
  _Pragma("unroll")                                                             \
  for (int k_ = 0; k_ < 4; ++k_) {                                              \
    const int s_  = wid + 8 * k_;                                               \
    const int st_ = (w_) * 32 + s_;                                             \
    if (st_ < NSTEPS) {                                                         \
      const char* rb_ = hist + s_ * HSLOT + l * 8;                              \
      float fx_ = 0.0f, fy_ = 0.0f, fz_ = 0.0f;                                 \
      _Pragma("unroll")                                                         \
      for (int m_ = 0; m_ < 8; ++m_) {                                          \
        const uint2 u_ = *(const uint2*)(rb_ + m_ * 512);                       \
        const half2v xy_ = __builtin_bit_cast(half2v, u_.x);                    \
        const half2v zp_ = __builtin_bit_cast(half2v, u_.y);                    \
        fx_ += (float)xy_[0]; fy_ += (float)xy_[1]; fz_ += (float)zp_[0];       \
      }                                                                         \
      const float sx_ = wave_sum64(fx_);                                        \
      const float sy_ = wave_sum64(fy_);                                        \
      const float sz_ = wave_sum64(fz_);                                        \
      if (l == 63) {                                                            \
        const float inv_ = 1.0f / 512.0f;                                       \
        const float mx_ = sx_ * inv_, my_ = sy_ * inv_, mz_ = sz_ * inv_;       \
        float* o_ = out + ((size_t)b * 256 + st_ + 1) * 6;                      \
        o_[0] = 0.5f * (1.0f + mx_); o_[1] = 0.5f * (1.0f - mx_);               \
        o_[2] = 0.5f * (1.0f + my_); o_[3] = 0.5f * (1.0f - my_);               \
        o_[4] = 0.5f * (1.0f + mz_); o_[5] = 0.5f * (1.0f - mz_);               \
      }                                                                         \
    }                                                                           \
  }                                                                             \
}

// One fused kernel: 32 blocks x 512 threads (8 waves = 2/SIMD). Block b owns
// group b (trajectories b*512..b*512+511). Time in 32-step windows: integrate
// (per-wave, R9 math) -> barrier -> block reduction -> barrier. Direct output.
__global__ __launch_bounds__(512, 2)
void sde_all(const float* __restrict__ inp, const float* __restrict__ wvec,
             float* __restrict__ out) {
  __shared__ alignas(16) char hist[HBYTES];
  const int b   = blockIdx.x;
  const int tid = threadIdx.x;
  const int wid = tid >> 6;
  const int l   = tid & 63;

  // trajectory n = b*512 + tid; eps = inputs[n % 32] = inputs[tid & 31]
  const float eps = inp[tid & 31];
  const f32x2 epack = {-eps * DT_F, eps * DT_F};
  const f32x2 mGD2  = {-GD, -GD};

  const float2* __restrict__ wrow =
      reinterpret_cast<const float2*>(wvec) + (size_t)(b * 512 + tid) * NSTEPS;
  char* const hb = hist + tid * 8;

  if (tid == 0) {   // t = 0: exact initial state (0,0,1)
    float* o = out + (size_t)b * 256 * 6;
    o[0] = 0.5f; o[1] = 0.5f; o[2] = 0.5f; o[3] = 0.5f;
    o[4] = 1.0f; o[5] = 0.0f;
  }

  f32x2 v = {0.0f, 0.0f};
  float z = 1.0f;
  float2 WA[32], WB[32];   // static indexing only (regs, not scratch)

  LOADW(WA, 0, 32);
  #pragma unroll 1
  for (int k = 0; k < 3; ++k) {          // windows 2k (WA), 2k+1 (WB)
    LOADW(WB, 2 * k + 1, 32);
    PROCW(WA, 32);
    __syncthreads();
    TAILW(2 * k);
    __syncthreads();
    LOADW(WA, 2 * k + 2, 32);
    PROCW(WB, 32);
    __syncthreads();
    TAILW(2 * k + 1);
    __syncthreads();
  }
  // windows 0..5 done; WA holds window 6.
  LOADW(WB, 7, 31);                      // last window: steps 224..254
  PROCW(WA, 32);
  __syncthreads();
  TAILW(6);
  __syncthreads();
  PROCW(WB, 31);
  __syncthreads();
  TAILW(7);                              // slots 0..30 (st<255 guard)
}

extern "C" void kernel_launch(void* const* d_in, const int* in_sizes, int n_in,
                              void* d_out, int out_size, void* d_ws, size_t ws_size,
                              hipStream_t stream) {
  (void)in_sizes; (void)n_in; (void)out_size; (void)d_ws; (void)ws_size;
  const float* inp  = (const float*)d_in[0];   // [32]
  const float* wvec = (const float*)d_in[1];   // [16384][255][2]
  float* out = (float*)d_out;                  // [32][256][6]

  sde_all<<<NGRP, 512, 0, stream>>>(inp, wvec, out);
}

// Round 12
// 30.306 us; speedup vs baseline: 1.5958x; 1.5958x over previous
//
#include <hip/hip_runtime.h>

// Problem constants
#define NSTEPS 255
#define NTRAJ  16384
#define NBLK   256          // integration blocks; 64 trajectories each
#define CH     15           // steps per prefetch chunk; 17*15 = 255

#define GAMMA_F 0.36f
#define OMEGA_F 5.0265f
#define DT_F    0.00390625f          // 2^-8
#define CW      0.0375f              // sqrt(GAMMA)*sqrt(DT) = 0.6/16 (exact)
#define GD      (GAMMA_F * DT_F)
#define OD      (OMEGA_F * DT_F)

// LDS state history (R7/R9-validated): [slot][lane] fp16x4, pitch 520 B.
#define PITCH  520
#define STATEB 132608        // 255*520 = 132600, padded

// d_ws layout: partial[256][255][3] f32 (783360 B), then int counters[32].
#define PARTB  783360

typedef __fp16 half2v __attribute__((ext_vector_type(2)));
typedef float  f32x2  __attribute__((ext_vector_type(2)));

__device__ __forceinline__ unsigned pk2(float a, float b) {
  half2v h = __builtin_amdgcn_cvt_pkrtz(a, b);
  return __builtin_bit_cast(unsigned, h);
}

// One Euler-Maruyama step, tree-reassociated (depth 4 vs 5):
//   nx = [x - eps*dt*y] + [-GD*x + 0     ] + [-(x*z)*w0 - cy*y]
//   ny = [y + eps*dt*x] + [-GD*y - OD*z  ] + [-(y*z)*w0 + cy*x]
//   nz = z + OD*y + (1 - z*z)*w0
#define STEP2(wx_, wy_, ii_) {                                                  \
  const float w0 = (wx_) * CW;                                                  \
  const float cy = (wy_) * CW;                                                  \
  const f32x2 sw = __builtin_shufflevector(v, v, 1, 0);    /* (y,x) */          \
  const f32x2 term1 = __builtin_elementwise_fma(epack, sw, v);                  \
  const f32x2 odz   = mOD2 * z;                            /* {0,-OD*z} */      \
  const f32x2 term2 = __builtin_elementwise_fma(mGD2, v, odz);                  \
  const f32x2 w0s = {w0, w0};                                                   \
  const f32x2 cys = {-cy, cy};                                                  \
  const f32x2 term3 = __builtin_elementwise_fma(-(v * z), w0s, sw * cys);       \
  const f32x2 t = (term1 + term2) + term3;                                      \
  const float a_ = __builtin_fmaf(OD, v[1], z);                                 \
  const float r_ = __builtin_fmaf(-(z * z), w0, w0);                            \
  v = t; z = a_ + r_;                                                           \
  *(uint2*)(sb + (ii_) * PITCH) = make_uint2(pk2(v[0], v[1]), pk2(z, 0.0f));    \
}

#define LOADC(BUF, CHUNK_) {                                                    \
  _Pragma("unroll")                                                             \
  for (int i_ = 0; i_ < CH; ++i_) BUF[i_] = wrow[(CHUNK_) * CH + i_];           \
}

#define PROC(BUF) {                                                             \
  _Pragma("unroll")                                                             \
  for (int i_ = 0; i_ < CH; ++i_) STEP2((BUF)[i_].x, (BUF)[i_].y, i_)           \
  sb += CH * PITCH;                                                             \
}

// grid = 256 blocks x 64 threads (1 wave); block g owns trajectories g*64..+63.
// R9-validated loop + tail, then last-block-done in-kernel finalize:
// counters start at ANY value (0xAA poison ok) — among the 8 atomicAdd returns
// per group exactly one is ==7 (mod 8); that block finalizes the group.
__global__ __launch_bounds__(64) void sde_integrate(const float* __restrict__ inp,
                                                    const float* __restrict__ wvec,
                                                    float* __restrict__ partial,
                                                    int* __restrict__ counters,
                                                    float* __restrict__ out) {
  __shared__ alignas(16) char smem[STATEB];
  __shared__ int sret;
  const int g = blockIdx.x, l = threadIdx.x;
  // trajectory n = g*64+l; eps = inputs[n % 32] = inputs[l & 31]
  const float eps = inp[l & 31];
  const f32x2 epack = {-eps * DT_F, eps * DT_F};
  const f32x2 mGD2  = {-GD, -GD};
  const f32x2 mOD2  = {0.0f, -OD};

  const float2* __restrict__ wrow =
      reinterpret_cast<const float2*>(wvec) + (size_t)(g * 64 + l) * NSTEPS;
  char* sb = smem + l * 8;             // slot 0, this lane's column

  f32x2 v = {0.0f, 0.0f};
  float z = 1.0f;

  float2 bufA[CH], bufB[CH], bufC[CH]; // static indexing only (regs)

  // prefetch distance 2: chunks c and c+1 in flight before computing c
  LOADC(bufA, 0);
  LOADC(bufB, 1);
  #pragma unroll 1
  for (int k = 0; k < 5; ++k) {        // chunks 3k..3k+2, loads 3k+2..3k+4
    LOADC(bufC, 3 * k + 2); PROC(bufA);
    LOADC(bufA, 3 * k + 3); PROC(bufB);
    LOADC(bufB, 3 * k + 4); PROC(bufC);
  }
  PROC(bufA);                          // chunk 15
  PROC(bufB);                          // chunk 16 (slots 240..254)

  __syncthreads();                     // single wave: cheap; orders LDS for tail

  // Tail (R9-validated): lane l reduces slots l, l+64, l+128, l+192 (<255).
  #pragma unroll
  for (int k = 0; k < 4; ++k) {
    const int s = l + 64 * k;
    if (s < NSTEPS) {
      const char* rb = smem + (size_t)s * PITCH;
      f32x2 sxy = {0.0f, 0.0f};
      float fz = 0.0f;
      #pragma unroll
      for (int j = 0; j < 64; ++j) {
        const uint2 u = *(const uint2*)(rb + j * 8);
        const half2v xy = __builtin_bit_cast(half2v, u.x);
        const half2v zp = __builtin_bit_cast(half2v, u.y);
        const f32x2 vxy = {(float)xy[0], (float)xy[1]};
        sxy += vxy;
        fz += (float)zp[0];
      }
      float* p = partial + ((size_t)g * NSTEPS + s) * 3;
      p[0] = sxy[0]; p[1] = sxy[1]; p[2] = fz;
    }
  }

  // ---- last-block-done finalize (device-scope release/acquire) ----
  __threadfence();                     // release: partials visible device-wide
  if (l == 0) sret = atomicAdd(counters + (g >> 3), 1);
  __syncthreads();
  if ((sret & 7) != 7) return;         // exactly one block per group proceeds
  __threadfence();                     // acquire: see all 8 blocks' partials

  const int grp = g >> 3;
  #pragma unroll
  for (int k = 0; k < 4; ++k) {
    const int t = l + 64 * k;          // 0..255
    float* o = out + ((size_t)grp * 256 + t) * 6;
    if (t == 0) {
      o[0] = 0.5f; o[1] = 0.5f; o[2] = 0.5f; o[3] = 0.5f;
      o[4] = 1.0f; o[5] = 0.0f;
    } else {
      float sx = 0.0f, sy = 0.0f, sz = 0.0f;
      #pragma unroll
      for (int j = 0; j < 8; ++j) {
        const float* p = partial + ((size_t)(grp * 8 + j) * NSTEPS + (t - 1)) * 3;
        sx += p[0]; sy += p[1]; sz += p[2];
      }
      const float inv = 1.0f / 512.0f;
      const float mx = sx * inv, my = sy * inv, mz = sz * inv;
      o[0] = 0.5f * (1.0f + mx);
      o[1] = 0.5f * (1.0f - mx);
      o[2] = 0.5f * (1.0f + my);
      o[3] = 0.5f * (1.0f - my);
      o[4] = 0.5f * (1.0f + mz);
      o[5] = 0.5f * (1.0f - mz);
    }
  }
}

extern "C" void kernel_launch(void* const* d_in, const int* in_sizes, int n_in,
                              void* d_out, int out_size, void* d_ws, size_t ws_size,
                              hipStream_t stream) {
  (void)in_sizes; (void)n_in; (void)out_size; (void)ws_size;
  const float* inp  = (const float*)d_in[0];   // [32]
  const float* wvec = (const float*)d_in[1];   // [16384][255][2]
  float* out      = (float*)d_out;             // [32][256][6]
  float* partial  = (float*)d_ws;              // [256][255][3] f32
  int*   counters = (int*)((char*)d_ws + PARTB);  // [32], any initial value ok

  sde_integrate<<<NBLK, 64, 0, stream>>>(inp, wvec, partial, counters, out);
}